// Round 1
// baseline (911.509 us; speedup 1.0000x reference)
//
#include <hip/hip_runtime.h>
#include <stdint.h>

#define DIM 64

// ---- build kernels ------------------------------------------------------

__global__ void count_kernel(const int* __restrict__ src, const int* __restrict__ dst,
                             int* __restrict__ outdeg, int* __restrict__ indeg, int e) {
    int i = blockIdx.x * blockDim.x + threadIdx.x;
    if (i < e) {
        atomicAdd(&outdeg[src[i]], 1);
        atomicAdd(&indeg[dst[i]], 1);
    }
}

// Single-block exclusive scan of indeg[0..n) -> offsets[0..n], offsets[n]=total.
__global__ void scan_kernel(const int* __restrict__ indeg, int* __restrict__ offsets, int n) {
    __shared__ int sums[1024];
    const int t = threadIdx.x;
    const int chunk = (n + 1023) / 1024;
    const int beg = t * chunk;
    const int end = min(beg + chunk, n);
    int s = 0;
    for (int i = beg; i < end; ++i) s += indeg[i];
    sums[t] = s;
    __syncthreads();
    // inclusive Hillis-Steele scan over the 1024 thread sums
    for (int off = 1; off < 1024; off <<= 1) {
        int add = (t >= off) ? sums[t - off] : 0;
        __syncthreads();
        sums[t] += add;
        __syncthreads();
    }
    int running = sums[t] - s;  // exclusive prefix for this thread's chunk
    for (int i = beg; i < end; ++i) {
        offsets[i] = running;
        running += indeg[i];
    }
    if (t == 1023) offsets[n] = sums[1023];
}

__global__ void dis_kernel(const int* __restrict__ outdeg, float* __restrict__ dis, int n) {
    int i = blockIdx.x * blockDim.x + threadIdx.x;
    if (i < n) {
        // reference deg = (#occurrences as source) + 1 (self loop); always > 0
        dis[i] = rsqrtf((float)outdeg[i] + 1.0f);
    }
}

__global__ void fill_kernel(const int* __restrict__ src, const int* __restrict__ dst,
                            const float* __restrict__ ew, const float* __restrict__ dis,
                            const int* __restrict__ offsets, int* __restrict__ cursor,
                            int* __restrict__ csr_src, float* __restrict__ csr_w, int e) {
    int i = blockIdx.x * blockDim.x + threadIdx.x;
    if (i < e) {
        int s = src[i], t = dst[i];
        float w = dis[s] * ew[i] * dis[t];
        int p = offsets[t] + atomicAdd(&cursor[t], 1);
        csr_src[p] = s;
        csr_w[p] = w;
    }
}

// ---- propagation --------------------------------------------------------
// One wave (64 lanes) per node; lane = feature index.
// mode 0: xstore = v; out  = 0.25*(xin + v)      (layer 1; xin == embedding)
// mode 1: xstore = v; out += 0.25*v              (layer 2)
// mode 2:              out += 0.25*v             (layer 3, no store)
__global__ void __launch_bounds__(256)
prop_kernel(const float* __restrict__ xin, float* __restrict__ xstore,
            float* __restrict__ out,
            const int* __restrict__ offsets, const int* __restrict__ csr_src,
            const float* __restrict__ csr_w, const float* __restrict__ dis,
            int n, int mode) {
    const int lane = threadIdx.x & 63;
    const int node = blockIdx.x * (blockDim.x >> 6) + (threadIdx.x >> 6);
    if (node >= n) return;

    const int beg = offsets[node];
    const int end = offsets[node + 1];
    const float d = dis[node];
    const int o = node * DIM + lane;

    float acc = d * d * xin[o];  // self-loop: norm = dis[i]^2, weight 1
    for (int p = beg; p < end; ++p) {
        int s = csr_src[p];       // wave-uniform
        float w = csr_w[p];       // wave-uniform
        acc = fmaf(w, xin[s * DIM + lane], acc);  // coalesced 256B gather
    }

    if (mode != 2) xstore[o] = acc;
    if (mode == 0) out[o] = 0.25f * (xin[o] + acc);
    else           out[o] += 0.25f * acc;
}

// ---- launch -------------------------------------------------------------

extern "C" void kernel_launch(void* const* d_in, const int* in_sizes, int n_in,
                              void* d_out, int out_size, void* d_ws, size_t ws_size,
                              hipStream_t stream) {
    const float* emb = (const float*)d_in[0];   // [N, 64] fp32
    const float* ew  = (const float*)d_in[1];   // [E] fp32
    const int*   ei  = (const int*)d_in[2];     // [2, E] int32
    const int E = in_sizes[2] / 2;
    const int N = in_sizes[0] / DIM;
    const int* src = ei;        // edge_index[0] = source j
    const int* dst = ei + E;    // edge_index[1] = target i
    float* out = (float*)d_out;

    // workspace layout (all 4-byte types; ~66 MB total)
    char* w = (char*)d_ws;
    int* outdeg  = (int*)w;  w += (size_t)N * 4;
    int* indeg   = (int*)w;  w += (size_t)N * 4;
    int* cursor  = (int*)w;  w += (size_t)N * 4;
    int* offsets = (int*)w;  w += (size_t)(N + 1) * 4;
    float* dis   = (float*)w; w += (size_t)N * 4;
    w = (char*)(((uintptr_t)w + 255) & ~(uintptr_t)255);
    int* csr_src = (int*)w;  w += (size_t)E * 4;
    float* csr_w = (float*)w; w += (size_t)E * 4;
    w = (char*)(((uintptr_t)w + 255) & ~(uintptr_t)255);
    float* xa    = (float*)w; w += (size_t)N * DIM * 4;
    float* xb    = (float*)w; w += (size_t)N * DIM * 4;

    // zero outdeg, indeg, cursor (contiguous)
    hipMemsetAsync(outdeg, 0, (size_t)3 * N * 4, stream);

    const int TB = 256;
    count_kernel<<<(E + TB - 1) / TB, TB, 0, stream>>>(src, dst, outdeg, indeg, E);
    scan_kernel<<<1, 1024, 0, stream>>>(indeg, offsets, N);
    dis_kernel<<<(N + TB - 1) / TB, TB, 0, stream>>>(outdeg, dis, N);
    fill_kernel<<<(E + TB - 1) / TB, TB, 0, stream>>>(src, dst, ew, dis, offsets, cursor,
                                                      csr_src, csr_w, E);

    const int WPB = TB / 64;  // 4 nodes (waves) per block
    dim3 grid((N + WPB - 1) / WPB), block(TB);
    prop_kernel<<<grid, block, 0, stream>>>(emb, xa, out, offsets, csr_src, csr_w, dis, N, 0);
    prop_kernel<<<grid, block, 0, stream>>>(xa, xb, out, offsets, csr_src, csr_w, dis, N, 1);
    prop_kernel<<<grid, block, 0, stream>>>(xb, nullptr, out, offsets, csr_src, csr_w, dis, N, 2);
}

// Round 2
// 511.677 us; speedup vs baseline: 1.7814x; 1.7814x over previous
//
#include <hip/hip_runtime.h>
#include <stdint.h>

#define DIM 64
#define SCAN_TILE 1024   // elements per scan block (256 threads x 4)

// ---- build kernels ------------------------------------------------------

__global__ void count_kernel(const int* __restrict__ src, const int* __restrict__ dst,
                             int* __restrict__ outdeg, int* __restrict__ indeg, int e) {
    int i = blockIdx.x * blockDim.x + threadIdx.x;
    if (i < e) {
        atomicAdd(&outdeg[src[i]], 1);
        atomicAdd(&indeg[dst[i]], 1);
    }
}

// Phase 1: per-tile sums of indeg. 256 threads x 4 elements, coalesced int4.
__global__ void __launch_bounds__(256)
scan_partial(const int* __restrict__ indeg, int* __restrict__ partial, int n) {
    __shared__ int wsum[4];
    const int tid = threadIdx.x;
    const int base = blockIdx.x * SCAN_TILE + tid * 4;
    int s = 0;
    if (base + 3 < n) {
        int4 v = *(const int4*)(indeg + base);
        s = v.x + v.y + v.z + v.w;
    } else {
        for (int i = 0; i < 4; ++i) if (base + i < n) s += indeg[base + i];
    }
    // wave reduce
    for (int off = 32; off > 0; off >>= 1) s += __shfl_down(s, off, 64);
    const int lane = tid & 63, wid = tid >> 6;
    if (lane == 0) wsum[wid] = s;
    __syncthreads();
    if (tid == 0) partial[blockIdx.x] = wsum[0] + wsum[1] + wsum[2] + wsum[3];
}

// Phase 2: single-block exclusive scan of the (<=1024) tile sums; writes total.
__global__ void scan_blocksums(int* __restrict__ partial, int* __restrict__ offsets,
                               int nblocks, int n) {
    __shared__ int buf[1024];
    const int t = threadIdx.x;
    int v = (t < nblocks) ? partial[t] : 0;
    buf[t] = v;
    __syncthreads();
    for (int off = 1; off < 1024; off <<= 1) {
        int add = (t >= off) ? buf[t - off] : 0;
        __syncthreads();
        buf[t] += add;
        __syncthreads();
    }
    if (t < nblocks) partial[t] = buf[t] - v;   // exclusive prefix, in place
    if (t == 1023) offsets[n] = buf[1023];      // grand total
}

// Phase 3: per-tile exclusive scan + write offsets. Also computes dis[] (each
// node visited exactly once here).
__global__ void __launch_bounds__(256)
scan_final(const int* __restrict__ indeg, const int* __restrict__ partial,
           int* __restrict__ offsets, const int* __restrict__ outdeg,
           float* __restrict__ dis, int n) {
    __shared__ int wpre[4];
    const int tid = threadIdx.x;
    const int base = blockIdx.x * SCAN_TILE + tid * 4;
    int v0 = 0, v1 = 0, v2 = 0, v3 = 0;
    if (base + 3 < n) {
        int4 v = *(const int4*)(indeg + base);
        v0 = v.x; v1 = v.y; v2 = v.z; v3 = v.w;
    } else {
        if (base + 0 < n) v0 = indeg[base + 0];
        if (base + 1 < n) v1 = indeg[base + 1];
        if (base + 2 < n) v2 = indeg[base + 2];
        if (base + 3 < n) v3 = indeg[base + 3];
    }
    const int s = v0 + v1 + v2 + v3;
    // inclusive wave scan
    int inc = s;
    const int lane = tid & 63, wid = tid >> 6;
    for (int off = 1; off < 64; off <<= 1) {
        int t = __shfl_up(inc, off, 64);
        if (lane >= off) inc += t;
    }
    if (lane == 63) wpre[wid] = inc;
    __syncthreads();
    if (tid == 0) {
        int r = 0;
        for (int w = 0; w < 4; ++w) { int t = wpre[w]; wpre[w] = r; r += t; }
    }
    __syncthreads();
    int run = (inc - s) + wpre[wid] + partial[blockIdx.x];
    if (base + 0 < n) { offsets[base + 0] = run; run += v0; dis[base + 0] = rsqrtf((float)outdeg[base + 0] + 1.0f); }
    if (base + 1 < n) { offsets[base + 1] = run; run += v1; dis[base + 1] = rsqrtf((float)outdeg[base + 1] + 1.0f); }
    if (base + 2 < n) { offsets[base + 2] = run; run += v2; dis[base + 2] = rsqrtf((float)outdeg[base + 2] + 1.0f); }
    if (base + 3 < n) { offsets[base + 3] = run; run += v3; dis[base + 3] = rsqrtf((float)outdeg[base + 3] + 1.0f); }
}

__global__ void fill_kernel(const int* __restrict__ src, const int* __restrict__ dst,
                            const float* __restrict__ ew, const float* __restrict__ dis,
                            const int* __restrict__ offsets, int* __restrict__ cursor,
                            int2* __restrict__ csr, int e) {
    int i = blockIdx.x * blockDim.x + threadIdx.x;
    if (i < e) {
        int s = src[i], t = dst[i];
        float w = dis[s] * ew[i] * dis[t];
        int p = offsets[t] + atomicAdd(&cursor[t], 1);
        csr[p] = make_int2(s, __float_as_int(w));
    }
}

// ---- propagation --------------------------------------------------------
// One wave (64 lanes) per node; lane = feature index. Edge loop unrolled x4
// so 4 independent 256B gathers are in flight per wave.
// mode 0: xstore = v; out  = 0.25*(xin + v)      (layer 1; xin == embedding)
// mode 1: xstore = v; out += 0.25*v              (layer 2)
// mode 2:              out += 0.25*v             (layer 3, no store)
__global__ void __launch_bounds__(256)
prop_kernel(const float* __restrict__ xin, float* __restrict__ xstore,
            float* __restrict__ out,
            const int* __restrict__ offsets, const int2* __restrict__ csr,
            const float* __restrict__ dis, int n, int mode) {
    const int lane = threadIdx.x & 63;
    const int node = blockIdx.x * (blockDim.x >> 6) + (threadIdx.x >> 6);
    if (node >= n) return;

    const int beg = offsets[node];
    const int end = offsets[node + 1];
    const float d = dis[node];
    const int o = node * DIM + lane;

    float acc = d * d * xin[o];  // self-loop: norm = dis[i]^2, weight 1
    int p = beg;
    for (; p + 4 <= end; p += 4) {
        int2 e0 = csr[p + 0];
        int2 e1 = csr[p + 1];
        int2 e2 = csr[p + 2];
        int2 e3 = csr[p + 3];
        float x0 = xin[e0.x * DIM + lane];
        float x1 = xin[e1.x * DIM + lane];
        float x2 = xin[e2.x * DIM + lane];
        float x3 = xin[e3.x * DIM + lane];
        acc = fmaf(__int_as_float(e0.y), x0, acc);
        acc = fmaf(__int_as_float(e1.y), x1, acc);
        acc = fmaf(__int_as_float(e2.y), x2, acc);
        acc = fmaf(__int_as_float(e3.y), x3, acc);
    }
    for (; p < end; ++p) {
        int2 e = csr[p];
        acc = fmaf(__int_as_float(e.y), xin[e.x * DIM + lane], acc);
    }

    if (mode != 2) xstore[o] = acc;
    if (mode == 0) out[o] = 0.25f * (xin[o] + acc);
    else           out[o] += 0.25f * acc;
}

// ---- launch -------------------------------------------------------------

extern "C" void kernel_launch(void* const* d_in, const int* in_sizes, int n_in,
                              void* d_out, int out_size, void* d_ws, size_t ws_size,
                              hipStream_t stream) {
    const float* emb = (const float*)d_in[0];   // [N, 64] fp32
    const float* ew  = (const float*)d_in[1];   // [E] fp32
    const int*   ei  = (const int*)d_in[2];     // [2, E] int32
    const int E = in_sizes[2] / 2;
    const int N = in_sizes[0] / DIM;
    const int* src = ei;        // edge_index[0] = source j
    const int* dst = ei + E;    // edge_index[1] = target i
    float* out = (float*)d_out;

    const int nscan = (N + SCAN_TILE - 1) / SCAN_TILE;  // tiles (<=1024 supported)

    // workspace layout
    char* w = (char*)d_ws;
    int* outdeg  = (int*)w;  w += (size_t)N * 4;
    int* indeg   = (int*)w;  w += (size_t)N * 4;
    int* cursor  = (int*)w;  w += (size_t)N * 4;
    int* offsets = (int*)w;  w += (size_t)(N + 1) * 4;
    float* dis   = (float*)w; w += (size_t)N * 4;
    int* partial = (int*)w;  w += (size_t)1024 * 4;
    w = (char*)(((uintptr_t)w + 255) & ~(uintptr_t)255);
    int2* csr    = (int2*)w; w += (size_t)E * 8;
    w = (char*)(((uintptr_t)w + 255) & ~(uintptr_t)255);
    float* xa    = (float*)w; w += (size_t)N * DIM * 4;
    float* xb    = (float*)w; w += (size_t)N * DIM * 4;

    // zero outdeg, indeg, cursor (contiguous)
    hipMemsetAsync(outdeg, 0, (size_t)3 * N * 4, stream);

    const int TB = 256;
    count_kernel<<<(E + TB - 1) / TB, TB, 0, stream>>>(src, dst, outdeg, indeg, E);
    scan_partial<<<nscan, TB, 0, stream>>>(indeg, partial, N);
    scan_blocksums<<<1, 1024, 0, stream>>>(partial, offsets, nscan, N);
    scan_final<<<nscan, TB, 0, stream>>>(indeg, partial, offsets, outdeg, dis, N);
    fill_kernel<<<(E + TB - 1) / TB, TB, 0, stream>>>(src, dst, ew, dis, offsets, cursor,
                                                      csr, E);

    const int WPB = TB / 64;  // 4 nodes (waves) per block
    dim3 grid((N + WPB - 1) / WPB), block(TB);
    prop_kernel<<<grid, block, 0, stream>>>(emb, xa, out, offsets, csr, dis, N, 0);
    prop_kernel<<<grid, block, 0, stream>>>(xa, xb, out, offsets, csr, dis, N, 1);
    prop_kernel<<<grid, block, 0, stream>>>(xb, nullptr, out, offsets, csr, dis, N, 2);
}